// Round 6
// baseline (503.259 us; speedup 1.0000x reference)
//
#include <hip/hip_runtime.h>
#include <math.h>

// Fused dual-LeNet + len-19 full convolution + log.
// 2 samples (4 LeNet instances) per block, 256 threads, fits 64 VGPRs (no spill).
// Round-6 changes:
//  * s_p1 padded: ic stride 148 (mod32=20), inst stride 888 (mod32=24)
//    -> kills the 4-way bank conflict on conv2 row reads (R5: 4.18e7 conflict cyc).
//  * LDS 36.9 -> 31.5 KB (5 blocks/CU, occupancy 50->62.5% cap): images loaded
//    in two halves; pair-1 imgs parked in registers during conv1 pass A.
//  * softmax folded into the 38 output lanes (one fewer barrier + serial phase).

#define SPB 2            // samples per block
#define P1_IC  148       // s_p1 channel stride (padded, mod 32 = 20)
#define P1_IN  888       // s_p1 instance stride = 6*148 (mod 32 = 24)

__global__ __launch_bounds__(256) void lenet_fused(
    const float* __restrict__ x,     // [B,2,28,28]
    const float* __restrict__ cw1,   // [6,1,5,5]
    const float* __restrict__ cb1,   // [6]
    const float* __restrict__ cw2,   // [16,6,5,5]
    const float* __restrict__ cb2,   // [16]
    const float* __restrict__ fw1,   // [120,256]
    const float* __restrict__ fb1,   // [120]
    const float* __restrict__ fw2,   // [84,120]
    const float* __restrict__ fb2,   // [84]
    const float* __restrict__ fw3,   // [10,84]
    const float* __restrict__ fb3,   // [10]
    float* __restrict__ out)         // [B,19]
{
    const int tid = threadIdx.x;
    const int b0  = blockIdx.x * SPB;

    // pool: phase-disjoint reuse. Images (2 inst = 1568 fl) during conv1;
    // then p2(1024) f1(480) f2(336) log(40) = 1880 fl.
    __shared__ __align__(16) float s_pool[1880];         //  7520 B
    __shared__ __align__(16) float s_p1  [4 * P1_IN];    // 14208 B
    __shared__ __align__(16) float s_w1t [25 * 8];       //   800 B  conv1 W^T [k][o]
    __shared__ float s_b1[8];
    __shared__ __align__(16) float s_w2t [150 * 16];     //  9600 B  conv2 W^T [ic*25+k][o]
    __shared__ float s_b2[16];
    // total ~31.5 KiB -> 5 blocks/CU

    float* s_img  = s_pool;          // 1568 floats (2 inst x 784)
    float* s_p2   = s_pool;          // 1024
    float* s_f1   = s_pool + 1024;   // 480
    float* s_f2   = s_pool + 1504;   // 336
    float* s_log  = s_pool + 1840;   // 40

    // ---- stage pair-0 images to LDS; park pair-1 in registers ----
    const float4* xb = (const float4*)(x + (size_t)b0 * 1568);
    {
        float4* si = (float4*)s_img;
        si[tid] = xb[tid];                       // 256 of 392
        if (tid < 136) si[256 + tid] = xb[256 + tid];
    }
    float4 r0 = xb[392 + tid];                   // pair-1: 392 float4
    float4 r1;
    if (tid < 136) r1 = xb[648 + tid];

    // ---- stage conv weights (transposed) ----
    for (int i = tid; i < 150; i += 256) {       // cw1 -> [k][o], stride 8
        int o = i / 25, k = i % 25;
        s_w1t[k * 8 + o] = cw1[i];
    }
    for (int i = tid; i < 2400; i += 256) {      // cw2 -> [ic*25+k][o], stride 16
        int o = i / 150, r = i % 150;
        s_w2t[r * 16 + o] = cw2[i];
    }
    if (tid < 6)  s_b1[tid] = cb1[tid];
    if (tid < 16) s_b2[tid] = cb2[tid];
    __syncthreads();

    // ---- conv1 5x5 (1->6) + pool2x2 + relu : two passes of 432 tasks ----
#pragma unroll 1
    for (int pass = 0; pass < 2; ++pass) {
#pragma unroll 1
        for (int t = tid; t < 432; t += 256) {
            int o  = t % 6;  int u = t / 6;
            int g  = u % 3;  int v = u / 3;
            int py = v % 12; int ip = v / 12;      // ip in {0,1}

            float acc0[8], acc1[8];
#pragma unroll
            for (int i = 0; i < 8; ++i) { acc0[i] = 0.f; acc1[i] = 0.f; }

            const float* srow = &s_img[ip * 784 + (py * 2) * 28 + g * 8];
            const float* wt   = &s_w1t[o];

            // r = 0 : acc0 only
            {
                const float4* rp = (const float4*)(srow);
                float4 q0 = rp[0], q1 = rp[1], q2 = rp[2];
                float row[12] = {q0.x,q0.y,q0.z,q0.w,q1.x,q1.y,q1.z,q1.w,q2.x,q2.y,q2.z,q2.w};
#pragma unroll
                for (int kx = 0; kx < 5; ++kx) {
                    float wv = wt[kx * 8];
#pragma unroll
                    for (int cc = 0; cc < 8; ++cc)
                        acc0[cc] = fmaf(row[cc + kx], wv, acc0[cc]);
                }
            }
            // r = 1..4 : both windows
#pragma unroll 1
            for (int r = 1; r <= 4; ++r) {
                const float4* rp = (const float4*)(srow + r * 28);
                float4 q0 = rp[0], q1 = rp[1], q2 = rp[2];
                float row[12] = {q0.x,q0.y,q0.z,q0.w,q1.x,q1.y,q1.z,q1.w,q2.x,q2.y,q2.z,q2.w};
                const float* whi = wt + r * 40;
                const float* wlo = whi - 40;
#pragma unroll
                for (int kx = 0; kx < 5; ++kx) {
                    float wh = whi[kx * 8];
                    float wl = wlo[kx * 8];
#pragma unroll
                    for (int cc = 0; cc < 8; ++cc) {
                        acc0[cc] = fmaf(row[cc + kx], wh, acc0[cc]);
                        acc1[cc] = fmaf(row[cc + kx], wl, acc1[cc]);
                    }
                }
            }
            // r = 5 : acc1 only
            {
                const float4* rp = (const float4*)(srow + 5 * 28);
                float4 q0 = rp[0], q1 = rp[1], q2 = rp[2];
                float row[12] = {q0.x,q0.y,q0.z,q0.w,q1.x,q1.y,q1.z,q1.w,q2.x,q2.y,q2.z,q2.w};
                const float* wlo = wt + 4 * 40;
#pragma unroll
                for (int kx = 0; kx < 5; ++kx) {
                    float wl = wlo[kx * 8];
#pragma unroll
                    for (int cc = 0; cc < 8; ++cc)
                        acc1[cc] = fmaf(row[cc + kx], wl, acc1[cc]);
                }
            }
            float bsum = s_b1[o];
            float4 res;
            {
                float m0 = fmaxf(fmaxf(acc0[0], acc0[1]), fmaxf(acc1[0], acc1[1]));
                float m1 = fmaxf(fmaxf(acc0[2], acc0[3]), fmaxf(acc1[2], acc1[3]));
                float m2 = fmaxf(fmaxf(acc0[4], acc0[5]), fmaxf(acc1[4], acc1[5]));
                float m3 = fmaxf(fmaxf(acc0[6], acc0[7]), fmaxf(acc1[6], acc1[7]));
                res.x = fmaxf(m0 + bsum, 0.f);
                res.y = fmaxf(m1 + bsum, 0.f);
                res.z = fmaxf(m2 + bsum, 0.f);
                res.w = fmaxf(m3 + bsum, 0.f);
            }
            int inst = pass * 2 + ip;
            *(float4*)&s_p1[inst * P1_IN + o * P1_IC + py * 12 + g * 4] = res;
        }
        __syncthreads();
        if (pass == 0) {
            // restage pair-1 images from registers
            float4* si = (float4*)s_img;
            si[tid] = r0;
            if (tid < 136) si[256 + tid] = r1;
            __syncthreads();
        }
    }

    // ---- conv2 5x5 (6->16) + pool2x2 + relu : 512 tasks = 2 full rounds ----
#pragma unroll 1
    for (int t = tid; t < 512; t += 256) {
        int o    = t & 15; int u = t >> 4;
        int inst = u & 3;  int pp = u >> 2;
        int py   = pp >> 1, pxp = pp & 1;

        float acc0[4], acc1[4];
#pragma unroll
        for (int i = 0; i < 4; ++i) { acc0[i] = 0.f; acc1[i] = 0.f; }

        const float* pbase = &s_p1[inst * P1_IN + (py * 2) * 12 + pxp * 4];
        const float* wt    = &s_w2t[o];

#pragma unroll 1
        for (int ic = 0; ic < 6; ++ic) {
            const float* prow = pbase + ic * P1_IC;
            const float* wic  = wt + ic * 400;     // (ic*25)*16

            // r = 0
            {
                const float4* rp = (const float4*)(prow);
                float4 q0 = rp[0], q1 = rp[1];
                float row[8] = {q0.x,q0.y,q0.z,q0.w,q1.x,q1.y,q1.z,q1.w};
#pragma unroll
                for (int kx = 0; kx < 5; ++kx) {
                    float wv = wic[kx * 16];
#pragma unroll
                    for (int cc = 0; cc < 4; ++cc)
                        acc0[cc] = fmaf(row[cc + kx], wv, acc0[cc]);
                }
            }
            // r = 1..4
#pragma unroll 1
            for (int r = 1; r <= 4; ++r) {
                const float4* rp = (const float4*)(prow + r * 12);
                float4 q0 = rp[0], q1 = rp[1];
                float row[8] = {q0.x,q0.y,q0.z,q0.w,q1.x,q1.y,q1.z,q1.w};
                const float* whi = wic + r * 80;
                const float* wlo = whi - 80;
#pragma unroll
                for (int kx = 0; kx < 5; ++kx) {
                    float wh = whi[kx * 16];
                    float wl = wlo[kx * 16];
#pragma unroll
                    for (int cc = 0; cc < 4; ++cc) {
                        acc0[cc] = fmaf(row[cc + kx], wh, acc0[cc]);
                        acc1[cc] = fmaf(row[cc + kx], wl, acc1[cc]);
                    }
                }
            }
            // r = 5
            {
                const float4* rp = (const float4*)(prow + 5 * 12);
                float4 q0 = rp[0], q1 = rp[1];
                float row[8] = {q0.x,q0.y,q0.z,q0.w,q1.x,q1.y,q1.z,q1.w};
                const float* wlo = wic + 4 * 80;
#pragma unroll
                for (int kx = 0; kx < 5; ++kx) {
                    float wl = wlo[kx * 16];
#pragma unroll
                    for (int cc = 0; cc < 4; ++cc)
                        acc1[cc] = fmaf(row[cc + kx], wl, acc1[cc]);
                }
            }
        }
        float bsum = s_b2[o];
#pragma unroll
        for (int j = 0; j < 2; ++j) {
            float m = fmaxf(fmaxf(acc0[2*j], acc0[2*j+1]), fmaxf(acc1[2*j], acc1[2*j+1]));
            s_p2[inst * 256 + o * 16 + py * 4 + (pxp * 2 + j)] = fmaxf(m + bsum, 0.f);
        }
    }
    __syncthreads();

    // ---- fc1: 256 -> 120, relu. 240 lanes, 2 instances each ----
    if (tid < 240) {
        int o  = tid % 120;
        int pr = tid / 120;
        const float4* wr = (const float4*)(fw1 + o * 256);
        const float4* q0 = (const float4*)(s_p2 + (2 * pr    ) * 256);
        const float4* q1 = (const float4*)(s_p2 + (2 * pr + 1) * 256);
        float a0 = 0.f, a1 = 0.f;
#pragma unroll 4
        for (int k = 0; k < 64; ++k) {
            float4 w4 = wr[k];
            float4 p;
            p = q0[k]; a0 = fmaf(w4.x,p.x,a0); a0 = fmaf(w4.y,p.y,a0); a0 = fmaf(w4.z,p.z,a0); a0 = fmaf(w4.w,p.w,a0);
            p = q1[k]; a1 = fmaf(w4.x,p.x,a1); a1 = fmaf(w4.y,p.y,a1); a1 = fmaf(w4.z,p.z,a1); a1 = fmaf(w4.w,p.w,a1);
        }
        float bb = fb1[o];
        s_f1[(2 * pr    ) * 120 + o] = fmaxf(a0 + bb, 0.f);
        s_f1[(2 * pr + 1) * 120 + o] = fmaxf(a1 + bb, 0.f);
    }
    __syncthreads();

    // ---- fc2: 120 -> 84, relu. 168 lanes, 2 instances each ----
    if (tid < 168) {
        int o  = tid % 84;
        int pr = tid / 84;
        const float4* wr = (const float4*)(fw2 + o * 120);
        const float4* q0 = (const float4*)(s_f1 + (2 * pr    ) * 120);
        const float4* q1 = (const float4*)(s_f1 + (2 * pr + 1) * 120);
        float a0 = 0.f, a1 = 0.f;
#pragma unroll 5
        for (int k = 0; k < 30; ++k) {
            float4 w4 = wr[k];
            float4 p;
            p = q0[k]; a0 = fmaf(w4.x,p.x,a0); a0 = fmaf(w4.y,p.y,a0); a0 = fmaf(w4.z,p.z,a0); a0 = fmaf(w4.w,p.w,a0);
            p = q1[k]; a1 = fmaf(w4.x,p.x,a1); a1 = fmaf(w4.y,p.y,a1); a1 = fmaf(w4.z,p.z,a1); a1 = fmaf(w4.w,p.w,a1);
        }
        float bb = fb2[o];
        s_f2[(2 * pr    ) * 84 + o] = fmaxf(a0 + bb, 0.f);
        s_f2[(2 * pr + 1) * 84 + o] = fmaxf(a1 + bb, 0.f);
    }
    __syncthreads();

    // ---- fc3: 84 -> 10. 40 lanes ----
    if (tid < 40) {
        int o    = tid % 10;
        int inst = tid / 10;
        const float4* wr = (const float4*)(fw3 + o * 84);
        const float4* q0 = (const float4*)(s_f2 + inst * 84);
        float a0 = 0.f;
#pragma unroll
        for (int k = 0; k < 21; ++k) {
            float4 w4 = wr[k];
            float4 p = q0[k];
            a0 = fmaf(w4.x,p.x,a0); a0 = fmaf(w4.y,p.y,a0); a0 = fmaf(w4.z,p.z,a0); a0 = fmaf(w4.w,p.w,a0);
        }
        s_log[inst * 10 + o] = a0 + fb3[o];
    }
    __syncthreads();

    // ---- softmax (in-lane) + full convolution (len 19) + log ----
    if (tid < 19 * SPB) {
        int ls = tid / 19;
        int t  = tid % 19;
        const float* la = &s_log[(ls * 2 + 0) * 10];
        const float* lb = &s_log[(ls * 2 + 1) * 10];
        float pa[10], pb[10];
        float mxa = la[0], mxb = lb[0];
#pragma unroll
        for (int j = 1; j < 10; ++j) { mxa = fmaxf(mxa, la[j]); mxb = fmaxf(mxb, lb[j]); }
        float sa = 0.f, sb = 0.f;
#pragma unroll
        for (int j = 0; j < 10; ++j) {
            pa[j] = __expf(la[j] - mxa); sa += pa[j];
            pb[j] = __expf(lb[j] - mxb); sb += pb[j];
        }
        float inv = 1.f / (sa * sb);
        int jlo = t - 9 > 0 ? t - 9 : 0;
        int jhi = t < 9 ? t : 9;
        float z = 0.f;
        for (int j = jlo; j <= jhi; ++j)
            z += pa[j] * pb[t - j];
        out[(size_t)(b0 + ls) * 19 + t] = __logf(z * inv);
    }
}

extern "C" void kernel_launch(void* const* d_in, const int* in_sizes, int n_in,
                              void* d_out, int out_size, void* d_ws, size_t ws_size,
                              hipStream_t stream) {
    const float* x   = (const float*)d_in[0];
    const float* cw1 = (const float*)d_in[1];
    const float* cb1 = (const float*)d_in[2];
    const float* cw2 = (const float*)d_in[3];
    const float* cb2 = (const float*)d_in[4];
    const float* fw1 = (const float*)d_in[5];
    const float* fb1 = (const float*)d_in[6];
    const float* fw2 = (const float*)d_in[7];
    const float* fb2 = (const float*)d_in[8];
    const float* fw3 = (const float*)d_in[9];
    const float* fb3 = (const float*)d_in[10];
    float* out = (float*)d_out;

    const int B = in_sizes[0] / (2 * 28 * 28);   // 16384

    lenet_fused<<<B / SPB, 256, 0, stream>>>(x, cw1, cb1, cw2, cb2,
                                             fw1, fb1, fw2, fb2, fw3, fb3, out);
}